// Round 12
// baseline (960.683 us; speedup 1.0000x reference)
//
#include <hip/hip_runtime.h>
#include <cmath>

typedef unsigned short u16;
typedef unsigned int u32;
typedef short s16x8 __attribute__((ext_vector_type(8)));
typedef short s16x4 __attribute__((ext_vector_type(4)));
typedef float f32x4 __attribute__((ext_vector_type(4)));

#define DEV static __device__ __forceinline__

DEV float b2f(u16 h) { return __uint_as_float(((u32)h) << 16); }
DEV u16 f2b(float f) {
  u32 u = __float_as_uint(f);
  u = (u + 0x7FFFu + ((u >> 16) & 1u)) >> 16;
  return (u16)u;
}
DEV float siluf(float x) { return x / (1.f + __expf(-x)); }

DEV void gload16(const void* g, void* l) {
  __builtin_amdgcn_global_load_lds((const __attribute__((address_space(1))) void*)g,
                                   (__attribute__((address_space(3))) void*)l, 16, 0, 0);
}

DEV s16x8 lds_frag(const u16* buf, int row, int kg) {
  int lin = row * 64 + kg * 16;
  int adr = lin ^ (((row >> 1) & 3) << 4);
  return *(const s16x8*)((const char*)buf + adr);
}

// ====== 256x256 8-wave ring-4 GEMM (proven best for qkv): C = A*B^T =========
// MODE 0: bf16 out   MODE 1: f32 out   MODE 2: f32 out += Cin
template <int MODE>
__global__ __launch_bounds__(512, 1) void gemm_deep(const u16* __restrict__ A, const u16* __restrict__ B,
                                                    void* __restrict__ Cout, const float* __restrict__ Cin,
                                                    int ldc, int K, int gx) {
  __shared__ __align__(16) u16 Al[4][256 * 32];
  __shared__ __align__(16) u16 Bl[4][256 * 32];
  int tid = threadIdx.x, w = tid >> 6, l = tid & 63;
  int cpx = gx >> 3;
  int idx = blockIdx.x >> 3;
  int bx = (blockIdx.x & 7) * cpx + idx % cpx;
  int by = idx / cpx;
  const u16* Ab = A + (long)by * 256 * K;
  const u16* Bb = B + (long)bx * 256 * K;
  int wr = w >> 2, wc = w & 3;
  int fro = l & 15, kg = l >> 4;
  f32x4 acc[8][4] = {};
  int nk = K >> 5;

  auto stage = [&](int buf, int kt) {
    #pragma unroll
    for (int i = 0; i < 2; ++i) {
      int x = (tid + i * 512) * 16;
      int y = x ^ (((x >> 7) & 3) << 4);
      gload16(Ab + (long)(y >> 6) * K + kt * 32 + ((y & 63) >> 1), (char*)&Al[buf][0] + x);
    }
    #pragma unroll
    for (int i = 0; i < 2; ++i) {
      int x = (tid + i * 512) * 16;
      int y = x ^ (((x >> 7) & 3) << 4);
      gload16(Bb + (long)(y >> 6) * K + kt * 32 + ((y & 63) >> 1), (char*)&Bl[buf][0] + x);
    }
  };

  stage(0, 0);
  stage(1, 1);
  stage(2, 2);
  asm volatile("s_waitcnt vmcnt(8)" ::: "memory");
  __builtin_amdgcn_s_barrier();

  int cur = 0;
  for (int t = 0; t < nk; ++t) {
    const u16* Ac = &Al[cur][0];
    const u16* Bc = &Bl[cur][0];
    s16x8 af[8], bfr[4];
    #pragma unroll
    for (int m = 0; m < 8; ++m) af[m] = lds_frag(Ac, wr * 128 + m * 16 + fro, kg);
    #pragma unroll
    for (int n = 0; n < 4; ++n) bfr[n] = lds_frag(Bc, wc * 64 + n * 16 + fro, kg);
    if (t + 3 < nk) stage((cur + 3) & 3, t + 3);
    __builtin_amdgcn_s_setprio(1);
    #pragma unroll
    for (int m = 0; m < 8; ++m)
      #pragma unroll
      for (int n = 0; n < 4; ++n)
        acc[m][n] = __builtin_amdgcn_mfma_f32_16x16x32_bf16(af[m], bfr[n], acc[m][n], 0, 0, 0);
    __builtin_amdgcn_s_setprio(0);
    if (t + 3 < nk)      asm volatile("s_waitcnt vmcnt(8)" ::: "memory");
    else if (t + 2 < nk) asm volatile("s_waitcnt vmcnt(4)" ::: "memory");
    else if (t + 1 < nk) asm volatile("s_waitcnt vmcnt(0)" ::: "memory");
    __builtin_amdgcn_s_barrier();
    cur = (cur + 1) & 3;
  }

  long rbase = (long)by * 256 + wr * 128 + kg * 4;
  long cbase = (long)bx * 256 + wc * 64 + fro;
  #pragma unroll
  for (int m = 0; m < 8; ++m)
    #pragma unroll
    for (int n = 0; n < 4; ++n)
      #pragma unroll
      for (int j = 0; j < 4; ++j) {
        long r = rbase + m * 16 + j;
        long c = cbase + n * 16;
        float v = acc[m][n][j];
        if (MODE == 2) v += Cin[r * ldc + c];
        if (MODE == 0) ((u16*)Cout)[r * ldc + c] = f2b(v);
        else ((float*)Cout)[r * ldc + c] = v;
      }
}

// ============ 128x128 4-wave ring-3 GEMM (o-proj/final): proven 775 TF =======
template <int MODE>
__global__ __launch_bounds__(256, 3) void gemm128(const u16* __restrict__ A, const u16* __restrict__ B,
                                                  void* __restrict__ Cout, const float* __restrict__ Cin,
                                                  int ldc, int K, int gx) {
  __shared__ __align__(16) u16 Al[3][128 * 32];
  __shared__ __align__(16) u16 Bl[3][128 * 32];
  int tid = threadIdx.x, w = tid >> 6, l = tid & 63;
  int cpx = gx >> 3;
  int idx = blockIdx.x >> 3;
  int bx = (blockIdx.x & 7) * cpx + idx % cpx;
  int by = idx / cpx;
  const u16* Ab = A + (long)by * 128 * K;
  const u16* Bb = B + (long)bx * 128 * K;
  int wr = w >> 1, wc = w & 1;
  int fro = l & 15, kg = l >> 4;
  f32x4 acc[4][4] = {};
  int nk = K >> 5;

  auto stage = [&](int buf, int kt) {
    #pragma unroll
    for (int i = 0; i < 2; ++i) {
      int x = (tid + i * 256) * 16;
      int y = x ^ (((x >> 7) & 3) << 4);
      gload16(Ab + (long)(y >> 6) * K + kt * 32 + ((y & 63) >> 1), (char*)&Al[buf][0] + x);
      gload16(Bb + (long)(y >> 6) * K + kt * 32 + ((y & 63) >> 1), (char*)&Bl[buf][0] + x);
    }
  };

  stage(0, 0);
  stage(1, 1);
  asm volatile("s_waitcnt vmcnt(4)" ::: "memory");
  __builtin_amdgcn_s_barrier();

  int cur = 0;
  for (int t = 0; t < nk; ++t) {
    const u16* Ac = &Al[cur][0];
    const u16* Bc = &Bl[cur][0];
    s16x8 af[4], bfr[4];
    #pragma unroll
    for (int m = 0; m < 4; ++m) af[m] = lds_frag(Ac, wr * 64 + m * 16 + fro, kg);
    #pragma unroll
    for (int n = 0; n < 4; ++n) bfr[n] = lds_frag(Bc, wc * 64 + n * 16 + fro, kg);
    if (t + 2 < nk) {
      int nb = cur + 2; if (nb >= 3) nb -= 3;
      stage(nb, t + 2);
    }
    __builtin_amdgcn_s_setprio(1);
    #pragma unroll
    for (int m = 0; m < 4; ++m)
      #pragma unroll
      for (int n = 0; n < 4; ++n)
        acc[m][n] = __builtin_amdgcn_mfma_f32_16x16x32_bf16(af[m], bfr[n], acc[m][n], 0, 0, 0);
    __builtin_amdgcn_s_setprio(0);
    if (t + 2 < nk)      asm volatile("s_waitcnt vmcnt(4)" ::: "memory");
    else if (t + 1 < nk) asm volatile("s_waitcnt vmcnt(0)" ::: "memory");
    __builtin_amdgcn_s_barrier();
    if (++cur == 3) cur = 0;
  }

  long rbase = (long)by * 128 + wr * 64 + kg * 4;
  long cbase = (long)bx * 128 + wc * 64 + fro;
  #pragma unroll
  for (int m = 0; m < 4; ++m)
    #pragma unroll
    for (int n = 0; n < 4; ++n)
      #pragma unroll
      for (int j = 0; j < 4; ++j) {
        long r = rbase + m * 16 + j;
        long c = cbase + n * 16;
        float v = acc[m][n][j];
        if (MODE == 2) v += Cin[r * ldc + c];
        if (MODE == 0) ((u16*)Cout)[r * ldc + c] = f2b(v);
        else ((float*)Cout)[r * ldc + c] = v;
      }
}

// ---------------- batched bf16 GEMM (TTT): ring pipeline + flexible epilogue --
struct GemmDesc {
  const u16* A; const u16* B;
  float* C; const float* Cin;
  u16* Cb; u16* CbT;
  long sAb, sAh, sBb, sBh, sCb_, sCh_, sCbb, sCbh, sCtb, sCth;
  int lda, ldb, ldc, ldcb, ldct, K;
};
struct GemmBatch { GemmDesc d[5]; int nbh; };

__global__ __launch_bounds__(256, 3) void gemm_bt(GemmBatch gb) {
  int di = blockIdx.z / gb.nbh;
  int bh = blockIdx.z % gb.nbh;
  GemmDesc d = gb.d[di];
  __shared__ __align__(16) u16 As[3][4096];
  __shared__ __align__(16) u16 Bs[3][4096];
  int tid = threadIdx.x, w = tid >> 6, l = tid & 63;
  int b2 = bh >> 2, h2 = bh & 3;
  const u16* Ab = d.A + (long)b2 * d.sAb + (long)h2 * d.sAh + (long)blockIdx.y * 128 * d.lda;
  const u16* Bb = d.B + (long)b2 * d.sBb + (long)h2 * d.sBh + (long)blockIdx.x * 128 * d.ldb;
  f32x4 acc[4][4] = {};
  int nk = d.K >> 5;

  auto stage = [&](int buf, int kt) {
    #pragma unroll
    for (int i = 0; i < 2; ++i) {
      int x = (tid + i * 256) * 16;
      int y = x ^ (((x >> 7) & 3) << 4);
      gload16(Ab + (long)(y >> 6) * d.lda + kt * 32 + ((y & 63) >> 1), (char*)&As[buf][0] + x);
      gload16(Bb + (long)(y >> 6) * d.ldb + kt * 32 + ((y & 63) >> 1), (char*)&Bs[buf][0] + x);
    }
  };

  stage(0, 0);
  stage(1, 1);
  asm volatile("s_waitcnt vmcnt(4)" ::: "memory");
  __builtin_amdgcn_s_barrier();

  int wr = (w >> 1) * 64, wc = (w & 1) * 64;
  int fro = l & 15, kg = l >> 4;

  int cur = 0;
  for (int kt = 0; kt < nk; ++kt) {
    const u16* Ac = &As[cur][0];
    const u16* Bc = &Bs[cur][0];
    s16x8 af[4], bfr[4];
    #pragma unroll
    for (int m = 0; m < 4; ++m) af[m] = lds_frag(Ac, wr + m * 16 + fro, kg);
    #pragma unroll
    for (int n = 0; n < 4; ++n) bfr[n] = lds_frag(Bc, wc + n * 16 + fro, kg);
    if (kt + 2 < nk) {
      int nb = cur + 2; if (nb >= 3) nb -= 3;
      stage(nb, kt + 2);
    }
    __builtin_amdgcn_s_setprio(1);
    #pragma unroll
    for (int m = 0; m < 4; ++m)
      #pragma unroll
      for (int n = 0; n < 4; ++n)
        acc[m][n] = __builtin_amdgcn_mfma_f32_16x16x32_bf16(af[m], bfr[n], acc[m][n], 0, 0, 0);
    __builtin_amdgcn_s_setprio(0);
    if (kt + 2 < nk)      asm volatile("s_waitcnt vmcnt(4)" ::: "memory");
    else if (kt + 1 < nk) asm volatile("s_waitcnt vmcnt(0)" ::: "memory");
    __builtin_amdgcn_s_barrier();
    if (++cur == 3) cur = 0;
  }

  float* Cp = d.C ? d.C + (long)b2 * d.sCb_ + (long)h2 * d.sCh_ : nullptr;
  const float* Ci = d.Cin ? d.Cin + (long)b2 * d.sCb_ + (long)h2 * d.sCh_ : nullptr;
  u16* Cbp = d.Cb ? d.Cb + (long)b2 * d.sCbb + (long)h2 * d.sCbh : nullptr;
  u16* Ctp = d.CbT ? d.CbT + (long)b2 * d.sCtb + (long)h2 * d.sCth : nullptr;
  long rbase = (long)blockIdx.y * 128 + wr + kg * 4;
  long cbase = (long)blockIdx.x * 128 + wc + fro;
  #pragma unroll
  for (int m = 0; m < 4; ++m)
    #pragma unroll
    for (int n = 0; n < 4; ++n)
      #pragma unroll
      for (int j = 0; j < 4; ++j) {
        long r = rbase + m * 16 + j;
        long c = cbase + n * 16;
        float v = acc[m][n][j];
        if (Ci) v += Ci[r * d.ldc + c];
        if (Cp) Cp[r * d.ldc + c] = v;
        if (Cbp) Cbp[r * d.ldcb + c] = f2b(v);
        if (Ctp) Ctp[c * d.ldct + r] = f2b(v);
      }
}

// ---------------- TTT q-path fused: hq = silu(q@w0^T) * (q@w2^T) -------------
// Dual-B ring-3 GEMM; epilogue applies silu-mul and writes hq bf16 directly.
__global__ __launch_bounds__(256, 2) void ttt_qfuse(const u16* __restrict__ q, const u16* __restrict__ w0,
                                                    const u16* __restrict__ w2, u16* __restrict__ hq) {
  __shared__ __align__(16) u16 As[3][4096];
  __shared__ __align__(16) u16 B0s[3][4096];
  __shared__ __align__(16) u16 B1s[3][4096];
  int tid = threadIdx.x, w = tid >> 6, l = tid & 63;
  int bh = blockIdx.z, b2 = bh >> 2, h2 = bh & 3;
  const u16* Ab = q + (long)b2 * 4194304 + (long)h2 * 512 + (long)blockIdx.y * 128 * 2048;
  const u16* B0b = w0 + (long)bh * 262144 + (long)blockIdx.x * 128 * 512;
  const u16* B1b = w2 + (long)bh * 262144 + (long)blockIdx.x * 128 * 512;
  f32x4 acc0[4][4] = {}, acc1[4][4] = {};
  const int nk = 16;

  auto stage = [&](int buf, int kt) {
    #pragma unroll
    for (int i = 0; i < 2; ++i) {
      int x = (tid + i * 256) * 16;
      int y = x ^ (((x >> 7) & 3) << 4);
      gload16(Ab + (long)(y >> 6) * 2048 + kt * 32 + ((y & 63) >> 1), (char*)&As[buf][0] + x);
      gload16(B0b + (long)(y >> 6) * 512 + kt * 32 + ((y & 63) >> 1), (char*)&B0s[buf][0] + x);
      gload16(B1b + (long)(y >> 6) * 512 + kt * 32 + ((y & 63) >> 1), (char*)&B1s[buf][0] + x);
    }
  };

  stage(0, 0);
  stage(1, 1);
  asm volatile("s_waitcnt vmcnt(6)" ::: "memory");
  __builtin_amdgcn_s_barrier();

  int wr = (w >> 1) * 64, wc = (w & 1) * 64;
  int fro = l & 15, kg = l >> 4;
  int cur = 0;
  for (int kt = 0; kt < nk; ++kt) {
    const u16* Ac = &As[cur][0];
    const u16* B0c = &B0s[cur][0];
    const u16* B1c = &B1s[cur][0];
    s16x8 af[4], b0f[4], b1f[4];
    #pragma unroll
    for (int m = 0; m < 4; ++m) af[m] = lds_frag(Ac, wr + m * 16 + fro, kg);
    #pragma unroll
    for (int n = 0; n < 4; ++n) { b0f[n] = lds_frag(B0c, wc + n * 16 + fro, kg); b1f[n] = lds_frag(B1c, wc + n * 16 + fro, kg); }
    if (kt + 2 < nk) {
      int nb = cur + 2; if (nb >= 3) nb -= 3;
      stage(nb, kt + 2);
    }
    __builtin_amdgcn_s_setprio(1);
    #pragma unroll
    for (int m = 0; m < 4; ++m)
      #pragma unroll
      for (int n = 0; n < 4; ++n) {
        acc0[m][n] = __builtin_amdgcn_mfma_f32_16x16x32_bf16(af[m], b0f[n], acc0[m][n], 0, 0, 0);
        acc1[m][n] = __builtin_amdgcn_mfma_f32_16x16x32_bf16(af[m], b1f[n], acc1[m][n], 0, 0, 0);
      }
    __builtin_amdgcn_s_setprio(0);
    if (kt + 2 < nk)      asm volatile("s_waitcnt vmcnt(6)" ::: "memory");
    else if (kt + 1 < nk) asm volatile("s_waitcnt vmcnt(0)" ::: "memory");
    __builtin_amdgcn_s_barrier();
    if (++cur == 3) cur = 0;
  }

  u16* Hp = hq + (long)bh * 262144;
  long rbase = (long)blockIdx.y * 128 + wr + kg * 4;
  long cbase = (long)blockIdx.x * 128 + wc + fro;
  #pragma unroll
  for (int m = 0; m < 4; ++m)
    #pragma unroll
    for (int n = 0; n < 4; ++n)
      #pragma unroll
      for (int j = 0; j < 4; ++j) {
        long r = rbase + m * 16 + j;
        long c = cbase + n * 16;
        Hp[r * 512 + c] = f2b(siluf(acc0[m][n][j]) * acc1[m][n][j]);
      }
}

// ---------------- f32 -> bf16 convert, 3-way range dispatch ------------------
__global__ __launch_bounds__(256) void convk3(const float* __restrict__ s0, u16* __restrict__ d0, long n0,
                                              const float* __restrict__ s1, u16* __restrict__ d1, long n1,
                                              const float* __restrict__ s2, u16* __restrict__ d2) {
  long i = ((long)blockIdx.x * 256 + threadIdx.x) * 4;
  const float* s; u16* d;
  if (i < n0) { s = s0; d = d0; }
  else if (i < n0 + n1) { s = s1 - n0; d = d1 - n0; }
  else { s = s2 - n0 - n1; d = d2 - n0 - n1; }
  float4 v = *(const float4*)(s + i);
  u16 o[4] __attribute__((aligned(8))) = {f2b(v.x), f2b(v.y), f2b(v.z), f2b(v.w)};
  *(s16x4*)&d[i] = *(const s16x4*)o;
}

// ---------------- qk rmsnorm + rope (V handled by vtrans from qkv) ------------
__global__ __launch_bounds__(256) void norm_rope_kernel(const u16* __restrict__ qkv,
    const float* __restrict__ qw, const float* __restrict__ kw,
    u16* __restrict__ qg, u16* __restrict__ kg) {
  __shared__ float qsh[2048], ksh[2048];
  __shared__ float red[2][4];
  int t = blockIdx.x, tid = threadIdx.x, w = tid >> 6, l = tid & 63;
  int s = t & 2047;
  const u16* row = qkv + (long)t * 6144;
  s16x8 vq = *(const s16x8*)&row[tid * 8];
  s16x8 vk = *(const s16x8*)&row[2048 + tid * 8];
  float sq = 0.f, sk = 0.f;
  #pragma unroll
  for (int i = 0; i < 8; ++i) {
    float a = b2f((u16)vq[i]); qsh[tid * 8 + i] = a; sq += a * a;
    float c = b2f((u16)vk[i]); ksh[tid * 8 + i] = c; sk += c * c;
  }
  #pragma unroll
  for (int mk = 32; mk; mk >>= 1) { sq += __shfl_xor(sq, mk, 64); sk += __shfl_xor(sk, mk, 64); }
  if (l == 0) { red[0][w] = sq; red[1][w] = sk; }
  __syncthreads();
  float rq = rsqrtf((red[0][0] + red[0][1] + red[0][2] + red[0][3]) * (1.f / 2048.f) + 1e-6f);
  float rk = rsqrtf((red[1][0] + red[1][1] + red[1][2] + red[1][3]) * (1.f / 2048.f) + 1e-6f);
  const float lf = 13.122363377404329f / 64.f;   // ln(500000)/64
  #pragma unroll
  for (int ii = 0; ii < 4; ++ii) {
    int pid = tid + 256 * ii;
    int h = pid >> 6, dpos = pid & 63;
    float invf = expf(-(float)dpos * lf);
    float ang = (float)s * invf;
    float sn, cs;
    sincosf(ang, &sn, &cs);
    int i1 = h * 128 + dpos, i2 = i1 + 64;
    float q1 = qsh[i1] * rq * qw[i1], q2 = qsh[i2] * rq * qw[i2];
    qg[(long)t * 2048 + i1] = f2b(q1 * cs - q2 * sn);
    qg[(long)t * 2048 + i2] = f2b(q2 * cs + q1 * sn);
    float k1 = ksh[i1] * rk * kw[i1], k2v = ksh[i2] * rk * kw[i2];
    kg[(long)t * 2048 + i1] = f2b(k1 * cs - k2v * sn);
    kg[(long)t * 2048 + i2] = f2b(k2v * cs + k1 * sn);
  }
}

// ---------------- V transpose from qkv: [b,t,(qkv)h,d] -> [b,h,d,t] ----------
__global__ __launch_bounds__(256) void vtrans_kernel(const u16* __restrict__ qkv, u16* __restrict__ vT) {
  __shared__ u16 T[64][74];
  int tid = threadIdx.x;
  int bh = blockIdx.z, b = bh >> 4, h = bh & 15;
  int ts = blockIdx.x * 64, dg = blockIdx.y * 64;
  int r = tid >> 2, c0 = (tid & 3) * 16;
  const u16* src = qkv + ((long)b * 2048 + ts + r) * 6144 + 4096 + h * 128 + dg + c0;
  *(s16x8*)&T[r][c0] = *(const s16x8*)src;
  *(s16x8*)&T[r][c0 + 8] = *(const s16x8*)(src + 8);
  __syncthreads();
  int d = tid >> 2, tg = (tid & 3) * 16;
  u16 a[16] __attribute__((aligned(16)));
  #pragma unroll
  for (int j = 0; j < 16; ++j) a[j] = T[tg + j][d];
  u16* dst = vT + ((long)bh * 128 + dg + d) * 2048 + ts + tg;
  *(s16x8*)dst = ((const s16x8*)a)[0];
  *(s16x8*)(dst + 8) = ((const s16x8*)a)[1];
}

// ---------------- sliding-window flash attention (64-row q blocks) -----------
// bh-grouped XCD mapping (equal per-XCD work, L2-resident KV).
__global__ __launch_bounds__(256, 3) void attn_kernel(const u16* __restrict__ qg, const u16* __restrict__ kg,
                                                      const u16* __restrict__ vT, u16* __restrict__ og) {
  __shared__ __align__(16) u16 Ks[64][136];
  __shared__ __align__(16) u16 Vt[128][72];
  __shared__ __align__(16) u16 Ps[4][16][72];
  int tid = threadIdx.x, w = tid >> 6, l = tid & 63;
  int lid = blockIdx.x + 32 * (blockIdx.y + 16 * blockIdx.z);
  int nid = ((lid & 7) << 7) + (lid >> 3);
  int bh = nid >> 5;
  int h = bh & 15, b = bh >> 4;
  int qs = (nid & 31) * 64;
  long tokb = (long)b * 2048;
  int fr = l & 15, fg = l >> 4;
  int wrow = qs + w * 16;

  s16x8 qf[4];
  #pragma unroll
  for (int ks = 0; ks < 4; ++ks)
    qf[ks] = *(const s16x8*)&qg[(tokb + wrow + fr) * 2048 + h * 128 + ks * 32 + fg * 8];

  f32x4 oacc[8] = {};
  float mrun[4], lrun[4];
  #pragma unroll
  for (int j = 0; j < 4; ++j) { mrun[j] = -__builtin_inff(); lrun[j] = 0.f; }

  int lo = qs - 1023;
  int t0 = lo > 0 ? (lo >> 6) : 0;
  int t1 = (qs + 63) >> 6;
  const float scale = 0.088388347648318447f;  // 1/sqrt(128)

  const u16* kbase = kg + tokb * 2048 + h * 128;
  const u16* vbase = vT + (long)(b * 16 + h) * 128 * 2048;

  s16x8 kreg[4], vreg[4];
  auto loadrg = [&](int kvs) {
    #pragma unroll
    for (int it = 0; it < 4; ++it) {
      int idx = it * 256 + tid;
      kreg[it] = *(const s16x8*)&kbase[(long)(kvs + (idx >> 4)) * 2048 + (idx & 15) * 8];
      vreg[it] = *(const s16x8*)&vbase[(long)(idx >> 3) * 2048 + kvs + (idx & 7) * 8];
    }
  };
  auto writelds = [&]() {
    #pragma unroll
    for (int it = 0; it < 4; ++it) {
      int idx = it * 256 + tid;
      *(s16x8*)&Ks[idx >> 4][(idx & 15) * 8] = kreg[it];
      *(s16x8*)&Vt[idx >> 3][(idx & 7) * 8] = vreg[it];
    }
  };

  loadrg(t0 << 6);
  writelds();
  __syncthreads();

  for (int kt = t0; kt <= t1; ++kt) {
    int kvs = kt << 6;
    if (kt < t1) loadrg((kt + 1) << 6);
    bool active = (kvs <= wrow + 15);
    if (active) {
      f32x4 st[4] = {};
      #pragma unroll
      for (int ct = 0; ct < 4; ++ct)
        #pragma unroll
        for (int ks = 0; ks < 4; ++ks) {
          s16x8 kf = *(const s16x8*)&Ks[ct * 16 + fr][ks * 32 + fg * 8];
          st[ct] = __builtin_amdgcn_mfma_f32_16x16x32_bf16(qf[ks], kf, st[ct], 0, 0, 0);
        }
      bool needm = (kvs + 63 > wrow) || (kvs < wrow - 1008);
      float mx[4];
      #pragma unroll
      for (int j = 0; j < 4; ++j) mx[j] = -__builtin_inff();
      #pragma unroll
      for (int ct = 0; ct < 4; ++ct)
        #pragma unroll
        for (int j = 0; j < 4; ++j) {
          float s = st[ct][j] * scale;
          if (needm) {
            int r = wrow + fg * 4 + j;
            int c = kvs + ct * 16 + fr;
            if (c > r || (r - c) >= 1024) s = -__builtin_inff();
          }
          st[ct][j] = s;
          mx[j] = fmaxf(mx[j], s);
        }
      #pragma unroll
      for (int mk = 8; mk; mk >>= 1)
        #pragma unroll
        for (int j = 0; j < 4; ++j) mx[j] = fmaxf(mx[j], __shfl_xor(mx[j], mk, 64));
      float sc[4], nmu[4], rs[4];
      #pragma unroll
      for (int j = 0; j < 4; ++j) {
        float nm = fmaxf(mrun[j], mx[j]);
        nmu[j] = (nm == -__builtin_inff()) ? 0.f : nm;
        sc[j] = __expf(mrun[j] - nmu[j]);
        mrun[j] = nm;
        rs[j] = 0.f;
      }
      #pragma unroll
      for (int ct = 0; ct < 4; ++ct)
        #pragma unroll
        for (int j = 0; j < 4; ++j) {
          float p = __expf(st[ct][j] - nmu[j]);
          rs[j] += p;
          Ps[w][fg * 4 + j][ct * 16 + fr] = f2b(p);
        }
      #pragma unroll
      for (int mk = 8; mk; mk >>= 1)
        #pragma unroll
        for (int j = 0; j < 4; ++j) rs[j] += __shfl_xor(rs[j], mk, 64);
      #pragma unroll
      for (int j = 0; j < 4; ++j) lrun[j] = lrun[j] * sc[j] + rs[j];
      #pragma unroll
      for (int dt = 0; dt < 8; ++dt)
        #pragma unroll
        for (int j = 0; j < 4; ++j) oacc[dt][j] *= sc[j];
      #pragma unroll
      for (int kst = 0; kst < 2; ++kst) {
        s16x8 pf = *(const s16x8*)&Ps[w][fr][kst * 32 + fg * 8];
        #pragma unroll
        for (int dt = 0; dt < 8; ++dt) {
          s16x8 vf = *(const s16x8*)&Vt[dt * 16 + fr][kst * 32 + fg * 8];
          oacc[dt] = __builtin_amdgcn_mfma_f32_16x16x32_bf16(pf, vf, oacc[dt], 0, 0, 0);
        }
      }
    }
    __syncthreads();
    if (kt < t1) {
      writelds();
    }
    __syncthreads();
  }
  #pragma unroll
  for (int j = 0; j < 4; ++j) {
    float inv = 1.f / lrun[j];
    long rofs = (tokb + wrow + fg * 4 + j) * 2048 + h * 128;
    #pragma unroll
    for (int dt = 0; dt < 8; ++dt)
      og[rofs + dt * 16 + fr] = f2b(oacc[dt][j] * inv);
  }
}

// ---------------- rmsnorm of attn_out -> x (bf16) + lr = softplus(x@lrw^T) ---
__global__ __launch_bounds__(256) void rms_lr_kernel(const float* __restrict__ src, const float* __restrict__ wgt,
                                                     const float* __restrict__ lrw, const float* __restrict__ lrbias,
                                                     u16* __restrict__ dst, float* __restrict__ lrout, float base) {
  __shared__ float red[4];
  __shared__ float red12[4][12];
  int t = blockIdx.x, tid = threadIdx.x, w = tid >> 6, l = tid & 63;
  const float* row = src + (long)t * 2048;
  float v[8] __attribute__((aligned(16)));
  ((float4*)v)[0] = *(const float4*)&row[tid * 8];
  ((float4*)v)[1] = *(const float4*)&row[tid * 8 + 4];
  float ss = 0.f;
  #pragma unroll
  for (int i = 0; i < 8; ++i) ss += v[i] * v[i];
  #pragma unroll
  for (int mk = 32; mk; mk >>= 1) ss += __shfl_xor(ss, mk, 64);
  if (l == 0) red[w] = ss;
  __syncthreads();
  float r = rsqrtf((red[0] + red[1] + red[2] + red[3]) * (1.f / 2048.f) + 1e-6f);
  float x[8];
  #pragma unroll
  for (int i = 0; i < 8; ++i) {
    x[i] = v[i] * r * wgt[tid * 8 + i];
    dst[(long)t * 2048 + tid * 8 + i] = f2b(x[i]);
  }
  float acc[12];
  #pragma unroll
  for (int j = 0; j < 12; ++j) {
    const float4* w4 = (const float4*)(lrw + j * 2048 + tid * 8);
    float4 a = w4[0], bq = w4[1];
    acc[j] = x[0] * a.x + x[1] * a.y + x[2] * a.z + x[3] * a.w +
             x[4] * bq.x + x[5] * bq.y + x[6] * bq.z + x[7] * bq.w;
  }
  #pragma unroll
  for (int j = 0; j < 12; ++j)
    #pragma unroll
    for (int mk = 32; mk; mk >>= 1) acc[j] += __shfl_xor(acc[j], mk, 64);
  if (l == 0) {
    #pragma unroll
    for (int j = 0; j < 12; ++j) red12[w][j] = acc[j];
  }
  __syncthreads();
  if (tid < 12) {
    float s_ = red12[0][tid] + red12[1][tid] + red12[2][tid] + red12[3][tid] + lrbias[tid] + base;
    lrout[(long)t * 12 + tid] = (s_ > 20.f) ? s_ : log1pf(__expf(s_));
  }
}

// ---------------- silu + l2-normalize fq/fk, silu fv -------------------------
__global__ __launch_bounds__(256) void silu_norm_kernel(const u16* __restrict__ fqkv,
    u16* __restrict__ fqo, u16* __restrict__ fko, u16* __restrict__ fvo) {
  int t = blockIdx.x, tid = threadIdx.x, w = tid >> 6, l = tid & 63;
  const u16* row = fqkv + (long)t * 6144;
  {
    s16x8 rv = *(const s16x8*)&row[w * 512 + l * 8];
    float x[8]; float ss = 0.f;
    #pragma unroll
    for (int i = 0; i < 8; ++i) { x[i] = siluf(b2f((u16)rv[i])); ss += x[i] * x[i]; }
    #pragma unroll
    for (int mk = 32; mk; mk >>= 1) ss += __shfl_xor(ss, mk, 64);
    float sc = 1.f / fmaxf(sqrtf(ss), 1e-6f);
    #pragma unroll
    for (int i = 0; i < 8; ++i) fqo[(long)t * 2048 + w * 512 + l * 8 + i] = f2b(x[i] * sc);
  }
  {
    s16x8 rv = *(const s16x8*)&row[2048 + w * 512 + l * 8];
    float x[8]; float ss = 0.f;
    #pragma unroll
    for (int i = 0; i < 8; ++i) { x[i] = siluf(b2f((u16)rv[i])); ss += x[i] * x[i]; }
    #pragma unroll
    for (int mk = 32; mk; mk >>= 1) ss += __shfl_xor(ss, mk, 64);
    float sc = 1.f / fmaxf(sqrtf(ss), 1e-6f);
    #pragma unroll
    for (int i = 0; i < 8; ++i) fko[(long)t * 2048 + w * 512 + l * 8 + i] = f2b(x[i] * sc);
  }
  {
    s16x8 rv = *(const s16x8*)&row[4096 + tid * 8];
    #pragma unroll
    for (int i = 0; i < 8; ++i) fvo[(long)t * 2048 + tid * 8 + i] = f2b(siluf(b2f((u16)rv[i])));
  }
}

// ---------------- init fast weights (f32 + bf16 + w1^T bf16) -----------------
__global__ __launch_bounds__(256) void winit_kernel(const float* __restrict__ w0, const float* __restrict__ w1,
                                                    const float* __restrict__ w2,
                                                    float* __restrict__ wbuf0, u16* __restrict__ wb16) {
  long gid = (long)blockIdx.x * 256 + threadIdx.x;
  long e4 = gid * 4;
  int which = (int)(e4 >> 21);
  long rem = e4 & 2097151L;
  int bh = (int)(rem >> 18);
  long idx = rem & 262143L;
  int h = bh & 3;
  const float* src = (which == 0 ? w0 : which == 1 ? w1 : w2) + (long)h * 262144 + idx;
  float4 v = *(const float4*)src;
  *(float4*)(wbuf0 + e4) = v;
  u16 o[4] __attribute__((aligned(8))) = {f2b(v.x), f2b(v.y), f2b(v.z), f2b(v.w)};
  *(s16x4*)&wb16[e4] = *(const s16x4*)o;
  if (which == 1) {
    u16* wt = wb16 + 3L * 2097152 + (long)bh * 262144;
    int r = (int)(idx >> 9), c = (int)(idx & 511);
    wt[(long)(c + 0) * 512 + r] = o[0];
    wt[(long)(c + 1) * 512 + r] = o[1];
    wt[(long)(c + 2) * 512 + r] = o[2];
    wt[(long)(c + 3) * 512 + r] = o[3];
  }
}

// ---------------- TTT k-path elementwise + transposed bf16 outputs -----------
__global__ __launch_bounds__(256) void ttt_elem_kernel(
    const float* __restrict__ t5,
    u16* __restrict__ hidT, u16* __restrict__ dhbmT, u16* __restrict__ dgpT,
    const u16* __restrict__ fk, const u16* __restrict__ fv, const float* __restrict__ lr,
    u16* __restrict__ k0T, u16* __restrict__ k2T, u16* __restrict__ v1T, int ic) {
  __shared__ u16 T0[64][72], T1[64][72], T2[64][72];
  int tid = threadIdx.x;
  int bh = blockIdx.y, b = bh >> 2, h = bh & 3;
  int tc = (blockIdx.x >> 3) * 64, te = (blockIdx.x & 7) * 64;
  int r = tid >> 2, c0 = (tid & 3) * 16;
  long base = (long)bh * 262144 + (long)(tc + r) * 512 + te + c0;

  {
    float gk_[16] __attribute__((aligned(16)));
    float k2_[16] __attribute__((aligned(16)));
    float dh_[16] __attribute__((aligned(16)));
    const float* pgk = t5 + base;
    const float* pk2 = t5 + 2097152L + base;
    const float* pdh = t5 + 2L * 2097152 + base;
    #pragma unroll
    for (int q4 = 0; q4 < 4; ++q4) {
      ((float4*)gk_)[q4] = *(const float4*)(pgk + q4 * 4);
      ((float4*)k2_)[q4] = *(const float4*)(pk2 + q4 * 4);
      ((float4*)dh_)[q4] = *(const float4*)(pdh + q4 * 4);
    }
    #pragma unroll
    for (int i = 0; i < 16; ++i) {
      float sg = 1.f / (1.f + __expf(-gk_[i]));
      float sil = gk_[i] * sg;
      float hid = sil * k2_[i];
      float dhbm = dh_[i] * sil;
      float dgate = dh_[i] * k2_[i];
      float dgp = dgate * sg * (1.f + gk_[i] * (1.f - sg));
      T0[r][c0 + i] = f2b(hid);
      T1[r][c0 + i] = f2b(dhbm);
      T2[r][c0 + i] = f2b(dgp);
    }
  }
  __syncthreads();
  long obase = (long)bh * 262144 + (long)(te + r) * 512 + tc + c0;
  {
    u16 a0[16] __attribute__((aligned(16))), a1[16] __attribute__((aligned(16))), a2[16] __attribute__((aligned(16)));
    #pragma unroll
    for (int i = 0; i < 16; ++i) { a0[i] = T0[c0 + i][r]; a1[i] = T1[c0 + i][r]; a2[i] = T2[c0 + i][r]; }
    *(s16x8*)&hidT[obase] = ((const s16x8*)a0)[0];   *(s16x8*)&hidT[obase + 8] = ((const s16x8*)a0)[1];
    *(s16x8*)&dhbmT[obase] = ((const s16x8*)a1)[0];  *(s16x8*)&dhbmT[obase + 8] = ((const s16x8*)a1)[1];
    *(s16x8*)&dgpT[obase] = ((const s16x8*)a2)[0];   *(s16x8*)&dgpT[obase + 8] = ((const s16x8*)a2)[1];
  }
  __syncthreads();
  {
    long to = (long)b * 2048 + (long)ic * 512 + tc + r;
    float l0 = lr[to * 12 + h], l1 = lr[to * 12 + 4 + h], l2 = lr[to * 12 + 8 + h];
    long goff = to * 2048 + (long)h * 512 + te + c0;
    s16x8 ka = *(const s16x8*)&fk[goff];
    s16x8 kb8 = *(const s16x8*)&fk[goff + 8];
    s16x8 va = *(const s16x8*)&fv[goff];
    s16x8 vb8 = *(const s16x8*)&fv[goff + 8];
    #pragma unroll
    for (int i = 0; i < 8; ++i) {
      float kv1 = b2f((u16)ka[i]), kv2 = b2f((u16)kb8[i]);
      float vv1 = b2f((u16)va[i]), vv2 = b2f((u16)vb8[i]);
      T0[r][c0 + i] = f2b(kv1 * l0);      T0[r][c0 + 8 + i] = f2b(kv2 * l0);
      T1[r][c0 + i] = f2b(kv1 * l2);      T1[r][c0 + 8 + i] = f2b(kv2 * l2);
      T2[r][c0 + i] = f2b(vv1 * l1);      T2[r][c0 + 8 + i] = f2b(vv2 * l1);
    }
  }
  __syncthreads();
  {
    u16 a0[16] __attribute__((aligned(16))), a1[16] __attribute__((aligned(16))), a2[16] __attribute__((aligned(16)));
    #pragma unroll
    for (int i = 0; i < 16; ++i) { a0[i] = T0[c0 + i][r]; a1[i] = T1[c0 + i][r]; a2[i] = T2[c0 + i][r]; }
    *(s16x8*)&k0T[obase] = ((const s16x8*)a0)[0];  *(s16x8*)&k0T[obase + 8] = ((const s16x8*)a0)[1];
    *(s16x8*)&k2T[obase] = ((const s16x8*)a1)[0];  *(s16x8*)&k2T[obase + 8] = ((const s16x8*)a1)[1];
    *(s16x8*)&v1T[obase] = ((const s16x8*)a2)[0];  *(s16x8*)&v1T[obase + 8] = ((const s16x8*)a2)[1];
  }
}

// ---------------- o_fw rmsnorm (per token per head over 512) -----------------
__global__ __launch_bounds__(256) void ttt_norm_kernel(const u16* __restrict__ src, const float* __restrict__ wgt,
                                                       u16* __restrict__ dst) {
  int t = blockIdx.x, tid = threadIdx.x, w = tid >> 6, l = tid & 63;
  long off = (long)t * 2048 + w * 512 + l * 8;
  s16x8 rv = *(const s16x8*)&src[off];
  float x[8];
  float ss = 0.f;
  #pragma unroll
  for (int i = 0; i < 8; ++i) { x[i] = b2f((u16)rv[i]); ss += x[i] * x[i]; }
  #pragma unroll
  for (int mk = 32; mk; mk >>= 1) ss += __shfl_xor(ss, mk, 64);
  float r = rsqrtf(ss * (1.f / 512.f) + 1e-6f);
  #pragma unroll
  for (int i = 0; i < 8; ++i) dst[off + i] = f2b(x[i] * r * wgt[l * 8 + i]);
}

// =============================================================================
extern "C" void kernel_launch(void* const* d_in, const int* in_sizes, int n_in,
                              void* d_out, int out_size, void* d_ws, size_t ws_size,
                              hipStream_t stream) {
  const float* hidden     = (const float*)d_in[0];
  const float* attn_qkv_w = (const float*)d_in[1];
  const float* attn_o_w   = (const float*)d_in[2];
  const float* q_norm_w   = (const float*)d_in[3];
  const float* k_norm_w   = (const float*)d_in[4];
  const float* mlp_norm_w = (const float*)d_in[5];
  const float* mlp_qkv_w  = (const float*)d_in[6];
  const float* mlp_o_w    = (const float*)d_in[7];
  const float* lr_w       = (const float*)d_in[8];
  const float* lr_bias    = (const float*)d_in[9];
  const float* w0in       = (const float*)d_in[10];
  const float* w1in       = (const float*)d_in[11];
  const float* w2in       = (const float*)d_in[12];
  const float* ttt_w      = (const float*)d_in[13];
  float* out = (float*)d_out;

  char* ws = (char*)d_ws;
  u16* hbf   = (u16*)(ws + 0);             // 16.78 MB: hidden bf16 -> xb -> ofw
  u16* wqb   = (u16*)(ws + 16777216);      // 25.17 MB: attn_qkv_w -> mlp_qkv_w bf16
  u16* wob   = (u16*)(ws + 41943040);      //  8.39 MB: attn_o_w -> mlp_o_w bf16
  char* big  = ws + 50331648;              // 71.30 MB: qkv/fqkv bf16 + vT -> TTT temps
  u16* qbuf  = (u16*)(ws + 121634816);     // q -> fq
  u16* kbuf  = (u16*)(ws + 138412032);     // k -> fk
  u16* vbuf  = (u16*)(ws + 155189248);     // fv
  u16* obuf  = (u16*)(ws + 171966464);     // attn o bf16 -> o_fw_norm bf16
  float* lrb_ = (float*)(ws + 188743680);  // 196608 B
  float* wbuf = (float*)(ws + 188940288);  // 50.33 MB: fast weights f32 ping-pong
  u16* wb16  = (u16*)(ws + 239271936);     // 16.78 MB: w0b,w1b,w2b,w1Tb
  // total: 256,049,152 bytes (~244.2 MiB)

  u16* qkvb = (u16*)big;
  u16* vTb  = (u16*)(big + 50331648);      // 16.78 MB V^T (only live during attn)
  float* t5 = (float*)big;                 // TTT temps: gk, k2, dh (3 x 8MB f32)
  u16* hqb   = (u16*)(big + 25165824);
  u16* hidT  = (u16*)(big + 29360128);
  u16* dhbmT = (u16*)(big + 33554432);
  u16* dgpT  = (u16*)(big + 37748736);
  u16* k0T   = (u16*)(big + 41943040);
  u16* k2T   = (u16*)(big + 46137344);
  u16* v1T   = (u16*)(big + 50331648);
  u16* xb  = hbf;
  u16* ofw = hbf;

  // 1: convert hidden + attn weights to bf16 (one 3-range launch)
  convk3<<<24576, 256, 0, stream>>>(hidden, hbf, 8388608L,
                                    attn_qkv_w, wqb, 12582912L,
                                    attn_o_w, wob);
  // 4: qkv = hidden @ attn_qkv_w^T (bf16 out) — 256^2 ring-4 deep GEMM
  gemm_deep<0><<<384, 512, 0, stream>>>(hbf, wqb, qkvb, nullptr, 6144, 2048, 24);
  // 5: q/k rmsnorm + rope
  norm_rope_kernel<<<4096, 256, 0, stream>>>(qkvb, q_norm_w, k_norm_w, qbuf, kbuf);
  // 5b: transpose V (read directly from qkv) -> vT [b,h,d,t]
  vtrans_kernel<<<dim3(32, 2, 32), 256, 0, stream>>>(qkvb, vTb);
  // 6: sliding-window attention (64-row q blocks, bh-grouped XCD mapping)
  attn_kernel<<<dim3(32, 16, 2), 256, 0, stream>>>(qbuf, kbuf, vTb, obuf);
  // 7: attn_out = o @ attn_o_w^T -> d_out (f32)
  gemm128<1><<<512, 256, 0, stream>>>(obuf, wob, out, nullptr, 2048, 2048, 16);
  // 8: x = rmsnorm(attn_out) + lr = softplus(x@lr_w^T+...) fused
  float base_lr_inv = 0.001f + logf(-expm1f(-0.001f));
  rms_lr_kernel<<<4096, 256, 0, stream>>>(out, mlp_norm_w, lr_w, lr_bias, xb, lrb_, base_lr_inv);
  // 9: convert mlp weights (one 3-range launch; third range aliases tail)
  convk3<<<16384, 256, 0, stream>>>(mlp_qkv_w, wqb, 12582912L,
                                    mlp_o_w, wob, 4194304L,
                                    mlp_o_w, wob);
  // 11: fqkv = x @ mlp_qkv_w^T (bf16 out)
  gemm_deep<0><<<384, 512, 0, stream>>>(xb, wqb, qkvb, nullptr, 6144, 2048, 24);
  // 12: silu + normalize -> fq/fk/fv
  silu_norm_kernel<<<4096, 256, 0, stream>>>(qkvb, qbuf, kbuf, vbuf);
  // 13: init fast weights
  winit_kernel<<<6144, 256, 0, stream>>>(w0in, w1in, w2in, wbuf, wb16);

  // 14: TTT scan over 4 chunks
  for (int ic = 0; ic < 4; ++ic) {
    // Q: hq = silu(fq@w0^T) * (fq@w2^T)  (fused dual-B GEMM)
    ttt_qfuse<<<dim3(4, 4, 8), 256, 0, stream>>>(qbuf + (long)ic * 1048576,
                                                 wb16, wb16 + 2L * 2097152, hqb);
    // G1: gk, k2, dhid  (3 gemms x 8 bh)
    {
      GemmBatch g{}; g.nbh = 8;
      const u16* Asrc[3] = {kbuf, kbuf, vbuf};
      long Bwhich[3] = {0, 2, 3};
      for (int i = 0; i < 3; ++i) {
        GemmDesc& dd = g.d[i];
        dd.A = Asrc[i] + (long)ic * 1048576; dd.sAb = 4194304; dd.sAh = 512; dd.lda = 2048;
        dd.B = wb16 + Bwhich[i] * 2097152;   dd.sBb = 1048576; dd.sBh = 262144; dd.ldb = 512;
        dd.C = t5 + (long)i * 2097152;       dd.sCb_ = 1048576; dd.sCh_ = 262144; dd.ldc = 512;
        dd.K = 512;
      }
      gemm_bt<<<dim3(4, 4, 24), 256, 0, stream>>>(g);
    }
    // E: k-path elementwise + transposed bf16 outputs
    ttt_elem_kernel<<<dim3(64, 8), 256, 0, stream>>>(t5, hidT, dhbmT, dgpT,
                                                     kbuf, vbuf, lrb_, k0T, k2T, v1T, ic);
    // G2+G3 merged: oc GEMM + 3 weight-update GEMMs in one launch
    {
      GemmBatch g{}; g.nbh = 8;
      float* wc_ = wbuf + (long)(ic & 1) * 6291456;
      float* wn_ = wbuf + (long)((ic & 1) ^ 1) * 6291456;
      {
        GemmDesc& dd = g.d[0];
        dd.A = hqb; dd.sAb = 1048576; dd.sAh = 262144; dd.lda = 512;
        dd.B = wb16 + 2097152; dd.sBb = 1048576; dd.sBh = 262144; dd.ldb = 512;
        dd.Cb = ofw + (long)ic * 1048576; dd.sCbb = 4194304; dd.sCbh = 512; dd.ldcb = 2048;
        dd.K = 512;
      }
      const u16* A3[3] = {dgpT, v1T, dhbmT};
      const u16* B3[3] = {k0T, hidT, k2T};
      for (int i = 0; i < 3; ++i) {
        GemmDesc& dd = g.d[1 + i];
        dd.A = A3[i]; dd.sAb = 1048576; dd.sAh = 262144; dd.lda = 512;
        dd.B = B3[i]; dd.sBb = 1048576; dd.sBh = 262144; dd.ldb = 512;
        dd.Cin = wc_ + (long)i * 2097152; dd.C = wn_ + (long)i * 2097152;
        dd.sCb_ = 1048576; dd.sCh_ = 262144; dd.ldc = 512;
        dd.Cb = wb16 + (long)i * 2097152; dd.sCbb = 1048576; dd.sCbh = 262144; dd.ldcb = 512;
        if (i == 1) { dd.CbT = wb16 + 3L * 2097152; dd.sCtb = 1048576; dd.sCth = 262144; dd.ldct = 512; }
        dd.K = 512;
      }
      gemm_bt<<<dim3(4, 4, 32), 256, 0, stream>>>(g);
    }
  }
  // 15: o_fw rmsnorm
  ttt_norm_kernel<<<4096, 256, 0, stream>>>(ofw, ttt_w, obuf);
  // 16: d_out += o_fw_norm @ mlp_o_w^T
  gemm128<2><<<512, 256, 0, stream>>>(obuf, wob, out, out, 2048, 2048, 16);
  (void)in_sizes; (void)n_in; (void)out_size; (void)ws_size;
}

// Round 13
// 894.337 us; speedup vs baseline: 1.0742x; 1.0742x over previous
//
#include <hip/hip_runtime.h>
#include <cmath>

typedef unsigned short u16;
typedef unsigned int u32;
typedef short s16x8 __attribute__((ext_vector_type(8)));
typedef short s16x4 __attribute__((ext_vector_type(4)));
typedef float f32x4 __attribute__((ext_vector_type(4)));

#define DEV static __device__ __forceinline__

DEV float b2f(u16 h) { return __uint_as_float(((u32)h) << 16); }
DEV u16 f2b(float f) {
  u32 u = __float_as_uint(f);
  u = (u + 0x7FFFu + ((u >> 16) & 1u)) >> 16;
  return (u16)u;
}
DEV float siluf(float x) { return x / (1.f + __expf(-x)); }

DEV void gload16(const void* g, void* l) {
  __builtin_amdgcn_global_load_lds((const __attribute__((address_space(1))) void*)g,
                                   (__attribute__((address_space(3))) void*)l, 16, 0, 0);
}

DEV s16x8 lds_frag(const u16* buf, int row, int kg) {
  int lin = row * 64 + kg * 16;
  int adr = lin ^ (((row >> 1) & 3) << 4);
  return *(const s16x8*)((const char*)buf + adr);
}

// ====== 256x256 8-wave ring-4 GEMM (proven best for qkv): C = A*B^T =========
// MODE 0: bf16 out   MODE 1: f32 out   MODE 2: f32 out += Cin
template <int MODE>
__global__ __launch_bounds__(512, 1) void gemm_deep(const u16* __restrict__ A, const u16* __restrict__ B,
                                                    void* __restrict__ Cout, const float* __restrict__ Cin,
                                                    int ldc, int K, int gx) {
  __shared__ __align__(16) u16 Al[4][256 * 32];
  __shared__ __align__(16) u16 Bl[4][256 * 32];
  int tid = threadIdx.x, w = tid >> 6, l = tid & 63;
  int cpx = gx >> 3;
  int idx = blockIdx.x >> 3;
  int bx = (blockIdx.x & 7) * cpx + idx % cpx;
  int by = idx / cpx;
  const u16* Ab = A + (long)by * 256 * K;
  const u16* Bb = B + (long)bx * 256 * K;
  int wr = w >> 2, wc = w & 3;
  int fro = l & 15, kg = l >> 4;
  f32x4 acc[8][4] = {};
  int nk = K >> 5;

  auto stage = [&](int buf, int kt) {
    #pragma unroll
    for (int i = 0; i < 2; ++i) {
      int x = (tid + i * 512) * 16;
      int y = x ^ (((x >> 7) & 3) << 4);
      gload16(Ab + (long)(y >> 6) * K + kt * 32 + ((y & 63) >> 1), (char*)&Al[buf][0] + x);
    }
    #pragma unroll
    for (int i = 0; i < 2; ++i) {
      int x = (tid + i * 512) * 16;
      int y = x ^ (((x >> 7) & 3) << 4);
      gload16(Bb + (long)(y >> 6) * K + kt * 32 + ((y & 63) >> 1), (char*)&Bl[buf][0] + x);
    }
  };

  stage(0, 0);
  stage(1, 1);
  stage(2, 2);
  asm volatile("s_waitcnt vmcnt(8)" ::: "memory");
  __builtin_amdgcn_s_barrier();

  int cur = 0;
  for (int t = 0; t < nk; ++t) {
    const u16* Ac = &Al[cur][0];
    const u16* Bc = &Bl[cur][0];
    s16x8 af[8], bfr[4];
    #pragma unroll
    for (int m = 0; m < 8; ++m) af[m] = lds_frag(Ac, wr * 128 + m * 16 + fro, kg);
    #pragma unroll
    for (int n = 0; n < 4; ++n) bfr[n] = lds_frag(Bc, wc * 64 + n * 16 + fro, kg);
    if (t + 3 < nk) stage((cur + 3) & 3, t + 3);
    __builtin_amdgcn_s_setprio(1);
    #pragma unroll
    for (int m = 0; m < 8; ++m)
      #pragma unroll
      for (int n = 0; n < 4; ++n)
        acc[m][n] = __builtin_amdgcn_mfma_f32_16x16x32_bf16(af[m], bfr[n], acc[m][n], 0, 0, 0);
    __builtin_amdgcn_s_setprio(0);
    if (t + 3 < nk)      asm volatile("s_waitcnt vmcnt(8)" ::: "memory");
    else if (t + 2 < nk) asm volatile("s_waitcnt vmcnt(4)" ::: "memory");
    else if (t + 1 < nk) asm volatile("s_waitcnt vmcnt(0)" ::: "memory");
    __builtin_amdgcn_s_barrier();
    cur = (cur + 1) & 3;
  }

  long rbase = (long)by * 256 + wr * 128 + kg * 4;
  long cbase = (long)bx * 256 + wc * 64 + fro;
  #pragma unroll
  for (int m = 0; m < 8; ++m)
    #pragma unroll
    for (int n = 0; n < 4; ++n)
      #pragma unroll
      for (int j = 0; j < 4; ++j) {
        long r = rbase + m * 16 + j;
        long c = cbase + n * 16;
        float v = acc[m][n][j];
        if (MODE == 2) v += Cin[r * ldc + c];
        if (MODE == 0) ((u16*)Cout)[r * ldc + c] = f2b(v);
        else ((float*)Cout)[r * ldc + c] = v;
      }
}

// ============ 128x128 4-wave ring-3 GEMM (o-proj/final): proven 775 TF =======
template <int MODE>
__global__ __launch_bounds__(256, 3) void gemm128(const u16* __restrict__ A, const u16* __restrict__ B,
                                                  void* __restrict__ Cout, const float* __restrict__ Cin,
                                                  int ldc, int K, int gx) {
  __shared__ __align__(16) u16 Al[3][128 * 32];
  __shared__ __align__(16) u16 Bl[3][128 * 32];
  int tid = threadIdx.x, w = tid >> 6, l = tid & 63;
  int cpx = gx >> 3;
  int idx = blockIdx.x >> 3;
  int bx = (blockIdx.x & 7) * cpx + idx % cpx;
  int by = idx / cpx;
  const u16* Ab = A + (long)by * 128 * K;
  const u16* Bb = B + (long)bx * 128 * K;
  int wr = w >> 1, wc = w & 1;
  int fro = l & 15, kg = l >> 4;
  f32x4 acc[4][4] = {};
  int nk = K >> 5;

  auto stage = [&](int buf, int kt) {
    #pragma unroll
    for (int i = 0; i < 2; ++i) {
      int x = (tid + i * 256) * 16;
      int y = x ^ (((x >> 7) & 3) << 4);
      gload16(Ab + (long)(y >> 6) * K + kt * 32 + ((y & 63) >> 1), (char*)&Al[buf][0] + x);
      gload16(Bb + (long)(y >> 6) * K + kt * 32 + ((y & 63) >> 1), (char*)&Bl[buf][0] + x);
    }
  };

  stage(0, 0);
  stage(1, 1);
  asm volatile("s_waitcnt vmcnt(4)" ::: "memory");
  __builtin_amdgcn_s_barrier();

  int cur = 0;
  for (int t = 0; t < nk; ++t) {
    const u16* Ac = &Al[cur][0];
    const u16* Bc = &Bl[cur][0];
    s16x8 af[4], bfr[4];
    #pragma unroll
    for (int m = 0; m < 4; ++m) af[m] = lds_frag(Ac, wr * 64 + m * 16 + fro, kg);
    #pragma unroll
    for (int n = 0; n < 4; ++n) bfr[n] = lds_frag(Bc, wc * 64 + n * 16 + fro, kg);
    if (t + 2 < nk) {
      int nb = cur + 2; if (nb >= 3) nb -= 3;
      stage(nb, t + 2);
    }
    __builtin_amdgcn_s_setprio(1);
    #pragma unroll
    for (int m = 0; m < 4; ++m)
      #pragma unroll
      for (int n = 0; n < 4; ++n)
        acc[m][n] = __builtin_amdgcn_mfma_f32_16x16x32_bf16(af[m], bfr[n], acc[m][n], 0, 0, 0);
    __builtin_amdgcn_s_setprio(0);
    if (t + 2 < nk)      asm volatile("s_waitcnt vmcnt(4)" ::: "memory");
    else if (t + 1 < nk) asm volatile("s_waitcnt vmcnt(0)" ::: "memory");
    __builtin_amdgcn_s_barrier();
    if (++cur == 3) cur = 0;
  }

  long rbase = (long)by * 128 + wr * 64 + kg * 4;
  long cbase = (long)bx * 128 + wc * 64 + fro;
  #pragma unroll
  for (int m = 0; m < 4; ++m)
    #pragma unroll
    for (int n = 0; n < 4; ++n)
      #pragma unroll
      for (int j = 0; j < 4; ++j) {
        long r = rbase + m * 16 + j;
        long c = cbase + n * 16;
        float v = acc[m][n][j];
        if (MODE == 2) v += Cin[r * ldc + c];
        if (MODE == 0) ((u16*)Cout)[r * ldc + c] = f2b(v);
        else ((float*)Cout)[r * ldc + c] = v;
      }
}

// ---------------- batched bf16 GEMM (TTT): ring pipeline + flexible epilogue --
struct GemmDesc {
  const u16* A; const u16* B;
  float* C; const float* Cin;
  u16* Cb; u16* CbT;
  long sAb, sAh, sBb, sBh, sCb_, sCh_, sCbb, sCbh, sCtb, sCth;
  int lda, ldb, ldc, ldcb, ldct, K;
};
struct GemmBatch { GemmDesc d[5]; int nbh; };

__global__ __launch_bounds__(256, 3) void gemm_bt(GemmBatch gb) {
  int di = blockIdx.z / gb.nbh;
  int bh = blockIdx.z % gb.nbh;
  GemmDesc d = gb.d[di];
  __shared__ __align__(16) u16 As[3][4096];
  __shared__ __align__(16) u16 Bs[3][4096];
  int tid = threadIdx.x, w = tid >> 6, l = tid & 63;
  int b2 = bh >> 2, h2 = bh & 3;
  const u16* Ab = d.A + (long)b2 * d.sAb + (long)h2 * d.sAh + (long)blockIdx.y * 128 * d.lda;
  const u16* Bb = d.B + (long)b2 * d.sBb + (long)h2 * d.sBh + (long)blockIdx.x * 128 * d.ldb;
  f32x4 acc[4][4] = {};
  int nk = d.K >> 5;

  auto stage = [&](int buf, int kt) {
    #pragma unroll
    for (int i = 0; i < 2; ++i) {
      int x = (tid + i * 256) * 16;
      int y = x ^ (((x >> 7) & 3) << 4);
      gload16(Ab + (long)(y >> 6) * d.lda + kt * 32 + ((y & 63) >> 1), (char*)&As[buf][0] + x);
      gload16(Bb + (long)(y >> 6) * d.ldb + kt * 32 + ((y & 63) >> 1), (char*)&Bs[buf][0] + x);
    }
  };

  stage(0, 0);
  stage(1, 1);
  asm volatile("s_waitcnt vmcnt(4)" ::: "memory");
  __builtin_amdgcn_s_barrier();

  int wr = (w >> 1) * 64, wc = (w & 1) * 64;
  int fro = l & 15, kg = l >> 4;

  int cur = 0;
  for (int kt = 0; kt < nk; ++kt) {
    const u16* Ac = &As[cur][0];
    const u16* Bc = &Bs[cur][0];
    s16x8 af[4], bfr[4];
    #pragma unroll
    for (int m = 0; m < 4; ++m) af[m] = lds_frag(Ac, wr + m * 16 + fro, kg);
    #pragma unroll
    for (int n = 0; n < 4; ++n) bfr[n] = lds_frag(Bc, wc + n * 16 + fro, kg);
    if (kt + 2 < nk) {
      int nb = cur + 2; if (nb >= 3) nb -= 3;
      stage(nb, kt + 2);
    }
    __builtin_amdgcn_s_setprio(1);
    #pragma unroll
    for (int m = 0; m < 4; ++m)
      #pragma unroll
      for (int n = 0; n < 4; ++n)
        acc[m][n] = __builtin_amdgcn_mfma_f32_16x16x32_bf16(af[m], bfr[n], acc[m][n], 0, 0, 0);
    __builtin_amdgcn_s_setprio(0);
    if (kt + 2 < nk)      asm volatile("s_waitcnt vmcnt(4)" ::: "memory");
    else if (kt + 1 < nk) asm volatile("s_waitcnt vmcnt(0)" ::: "memory");
    __builtin_amdgcn_s_barrier();
    if (++cur == 3) cur = 0;
  }

  float* Cp = d.C ? d.C + (long)b2 * d.sCb_ + (long)h2 * d.sCh_ : nullptr;
  const float* Ci = d.Cin ? d.Cin + (long)b2 * d.sCb_ + (long)h2 * d.sCh_ : nullptr;
  u16* Cbp = d.Cb ? d.Cb + (long)b2 * d.sCbb + (long)h2 * d.sCbh : nullptr;
  u16* Ctp = d.CbT ? d.CbT + (long)b2 * d.sCtb + (long)h2 * d.sCth : nullptr;
  long rbase = (long)blockIdx.y * 128 + wr + kg * 4;
  long cbase = (long)blockIdx.x * 128 + wc + fro;
  #pragma unroll
  for (int m = 0; m < 4; ++m)
    #pragma unroll
    for (int n = 0; n < 4; ++n)
      #pragma unroll
      for (int j = 0; j < 4; ++j) {
        long r = rbase + m * 16 + j;
        long c = cbase + n * 16;
        float v = acc[m][n][j];
        if (Ci) v += Ci[r * d.ldc + c];
        if (Cp) Cp[r * d.ldc + c] = v;
        if (Cbp) Cbp[r * d.ldcb + c] = f2b(v);
        if (Ctp) Ctp[c * d.ldct + r] = f2b(v);
      }
}

// ---------------- f32 -> bf16 convert, 3-way range dispatch ------------------
__global__ __launch_bounds__(256) void convk3(const float* __restrict__ s0, u16* __restrict__ d0, long n0,
                                              const float* __restrict__ s1, u16* __restrict__ d1, long n1,
                                              const float* __restrict__ s2, u16* __restrict__ d2) {
  long i = ((long)blockIdx.x * 256 + threadIdx.x) * 4;
  const float* s; u16* d;
  if (i < n0) { s = s0; d = d0; }
  else if (i < n0 + n1) { s = s1 - n0; d = d1 - n0; }
  else { s = s2 - n0 - n1; d = d2 - n0 - n1; }
  float4 v = *(const float4*)(s + i);
  u16 o[4] __attribute__((aligned(8))) = {f2b(v.x), f2b(v.y), f2b(v.z), f2b(v.w)};
  *(s16x4*)&d[i] = *(const s16x4*)o;
}

// ---------------- qk rmsnorm + rope + v passthrough --------------------------
__global__ __launch_bounds__(256) void norm_rope_kernel(const u16* __restrict__ qkv,
    const float* __restrict__ qw, const float* __restrict__ kw,
    u16* __restrict__ qg, u16* __restrict__ kg, u16* __restrict__ vg) {
  __shared__ float qsh[2048], ksh[2048];
  __shared__ float red[2][4];
  int t = blockIdx.x, tid = threadIdx.x, w = tid >> 6, l = tid & 63;
  int s = t & 2047;
  const u16* row = qkv + (long)t * 6144;
  s16x8 vq = *(const s16x8*)&row[tid * 8];
  s16x8 vk = *(const s16x8*)&row[2048 + tid * 8];
  float sq = 0.f, sk = 0.f;
  #pragma unroll
  for (int i = 0; i < 8; ++i) {
    float a = b2f((u16)vq[i]); qsh[tid * 8 + i] = a; sq += a * a;
    float c = b2f((u16)vk[i]); ksh[tid * 8 + i] = c; sk += c * c;
  }
  *(s16x8*)&vg[(long)t * 2048 + tid * 8] = *(const s16x8*)&row[4096 + tid * 8];
  #pragma unroll
  for (int mk = 32; mk; mk >>= 1) { sq += __shfl_xor(sq, mk, 64); sk += __shfl_xor(sk, mk, 64); }
  if (l == 0) { red[0][w] = sq; red[1][w] = sk; }
  __syncthreads();
  float rq = rsqrtf((red[0][0] + red[0][1] + red[0][2] + red[0][3]) * (1.f / 2048.f) + 1e-6f);
  float rk = rsqrtf((red[1][0] + red[1][1] + red[1][2] + red[1][3]) * (1.f / 2048.f) + 1e-6f);
  const float lf = 13.122363377404329f / 64.f;   // ln(500000)/64
  #pragma unroll
  for (int ii = 0; ii < 4; ++ii) {
    int pid = tid + 256 * ii;
    int h = pid >> 6, dpos = pid & 63;
    float invf = expf(-(float)dpos * lf);
    float ang = (float)s * invf;
    float sn, cs;
    sincosf(ang, &sn, &cs);
    int i1 = h * 128 + dpos, i2 = i1 + 64;
    float q1 = qsh[i1] * rq * qw[i1], q2 = qsh[i2] * rq * qw[i2];
    qg[(long)t * 2048 + i1] = f2b(q1 * cs - q2 * sn);
    qg[(long)t * 2048 + i2] = f2b(q2 * cs + q1 * sn);
    float k1 = ksh[i1] * rk * kw[i1], k2v = ksh[i2] * rk * kw[i2];
    kg[(long)t * 2048 + i1] = f2b(k1 * cs - k2v * sn);
    kg[(long)t * 2048 + i2] = f2b(k2v * cs + k1 * sn);
  }
}

// ---------------- V transpose: [b,t,h,d] -> [b,h,d,t] ------------------------
__global__ __launch_bounds__(256) void vtrans_kernel(const u16* __restrict__ v, u16* __restrict__ vT) {
  __shared__ u16 T[64][74];
  int tid = threadIdx.x;
  int bh = blockIdx.z, b = bh >> 4, h = bh & 15;
  int ts = blockIdx.x * 64, dg = blockIdx.y * 64;
  int r = tid >> 2, c0 = (tid & 3) * 16;
  const u16* src = v + ((long)b * 2048 + ts + r) * 2048 + h * 128 + dg + c0;
  *(s16x8*)&T[r][c0] = *(const s16x8*)src;
  *(s16x8*)&T[r][c0 + 8] = *(const s16x8*)(src + 8);
  __syncthreads();
  int d = tid >> 2, tg = (tid & 3) * 16;
  u16 a[16] __attribute__((aligned(16)));
  #pragma unroll
  for (int j = 0; j < 16; ++j) a[j] = T[tg + j][d];
  u16* dst = vT + ((long)bh * 128 + dg + d) * 2048 + ts + tg;
  *(s16x8*)dst = ((const s16x8*)a)[0];
  *(s16x8*)(dst + 8) = ((const s16x8*)a)[1];
}

// ---------------- sliding-window flash attention (64-row q blocks) -----------
// bh-grouped XCD mapping (equal per-XCD work, L2-resident KV).
__global__ __launch_bounds__(256, 3) void attn_kernel(const u16* __restrict__ qg, const u16* __restrict__ kg,
                                                      const u16* __restrict__ vT, u16* __restrict__ og) {
  __shared__ __align__(16) u16 Ks[64][136];
  __shared__ __align__(16) u16 Vt[128][72];
  __shared__ __align__(16) u16 Ps[4][16][72];
  int tid = threadIdx.x, w = tid >> 6, l = tid & 63;
  int lid = blockIdx.x + 32 * (blockIdx.y + 16 * blockIdx.z);
  int nid = ((lid & 7) << 7) + (lid >> 3);
  int bh = nid >> 5;
  int h = bh & 15, b = bh >> 4;
  int qs = (nid & 31) * 64;
  long tokb = (long)b * 2048;
  int fr = l & 15, fg = l >> 4;
  int wrow = qs + w * 16;

  s16x8 qf[4];
  #pragma unroll
  for (int ks = 0; ks < 4; ++ks)
    qf[ks] = *(const s16x8*)&qg[(tokb + wrow + fr) * 2048 + h * 128 + ks * 32 + fg * 8];

  f32x4 oacc[8] = {};
  float mrun[4], lrun[4];
  #pragma unroll
  for (int j = 0; j < 4; ++j) { mrun[j] = -__builtin_inff(); lrun[j] = 0.f; }

  int lo = qs - 1023;
  int t0 = lo > 0 ? (lo >> 6) : 0;
  int t1 = (qs + 63) >> 6;
  const float scale = 0.088388347648318447f;  // 1/sqrt(128)

  const u16* kbase = kg + tokb * 2048 + h * 128;
  const u16* vbase = vT + (long)(b * 16 + h) * 128 * 2048;

  s16x8 kreg[4], vreg[4];
  auto loadrg = [&](int kvs) {
    #pragma unroll
    for (int it = 0; it < 4; ++it) {
      int idx = it * 256 + tid;
      kreg[it] = *(const s16x8*)&kbase[(long)(kvs + (idx >> 4)) * 2048 + (idx & 15) * 8];
      vreg[it] = *(const s16x8*)&vbase[(long)(idx >> 3) * 2048 + kvs + (idx & 7) * 8];
    }
  };
  auto writelds = [&]() {
    #pragma unroll
    for (int it = 0; it < 4; ++it) {
      int idx = it * 256 + tid;
      *(s16x8*)&Ks[idx >> 4][(idx & 15) * 8] = kreg[it];
      *(s16x8*)&Vt[idx >> 3][(idx & 7) * 8] = vreg[it];
    }
  };

  loadrg(t0 << 6);
  writelds();
  __syncthreads();

  for (int kt = t0; kt <= t1; ++kt) {
    int kvs = kt << 6;
    if (kt < t1) loadrg((kt + 1) << 6);
    bool active = (kvs <= wrow + 15);
    if (active) {
      f32x4 st[4] = {};
      #pragma unroll
      for (int ct = 0; ct < 4; ++ct)
        #pragma unroll
        for (int ks = 0; ks < 4; ++ks) {
          s16x8 kf = *(const s16x8*)&Ks[ct * 16 + fr][ks * 32 + fg * 8];
          st[ct] = __builtin_amdgcn_mfma_f32_16x16x32_bf16(qf[ks], kf, st[ct], 0, 0, 0);
        }
      bool needm = (kvs + 63 > wrow) || (kvs < wrow - 1008);
      float mx[4];
      #pragma unroll
      for (int j = 0; j < 4; ++j) mx[j] = -__builtin_inff();
      #pragma unroll
      for (int ct = 0; ct < 4; ++ct)
        #pragma unroll
        for (int j = 0; j < 4; ++j) {
          float s = st[ct][j] * scale;
          if (needm) {
            int r = wrow + fg * 4 + j;
            int c = kvs + ct * 16 + fr;
            if (c > r || (r - c) >= 1024) s = -__builtin_inff();
          }
          st[ct][j] = s;
          mx[j] = fmaxf(mx[j], s);
        }
      #pragma unroll
      for (int mk = 8; mk; mk >>= 1)
        #pragma unroll
        for (int j = 0; j < 4; ++j) mx[j] = fmaxf(mx[j], __shfl_xor(mx[j], mk, 64));
      float sc[4], nmu[4], rs[4];
      #pragma unroll
      for (int j = 0; j < 4; ++j) {
        float nm = fmaxf(mrun[j], mx[j]);
        nmu[j] = (nm == -__builtin_inff()) ? 0.f : nm;
        sc[j] = __expf(mrun[j] - nmu[j]);
        mrun[j] = nm;
        rs[j] = 0.f;
      }
      #pragma unroll
      for (int ct = 0; ct < 4; ++ct)
        #pragma unroll
        for (int j = 0; j < 4; ++j) {
          float p = __expf(st[ct][j] - nmu[j]);
          rs[j] += p;
          Ps[w][fg * 4 + j][ct * 16 + fr] = f2b(p);
        }
      #pragma unroll
      for (int mk = 8; mk; mk >>= 1)
        #pragma unroll
        for (int j = 0; j < 4; ++j) rs[j] += __shfl_xor(rs[j], mk, 64);
      #pragma unroll
      for (int j = 0; j < 4; ++j) lrun[j] = lrun[j] * sc[j] + rs[j];
      #pragma unroll
      for (int dt = 0; dt < 8; ++dt)
        #pragma unroll
        for (int j = 0; j < 4; ++j) oacc[dt][j] *= sc[j];
      #pragma unroll
      for (int kst = 0; kst < 2; ++kst) {
        s16x8 pf = *(const s16x8*)&Ps[w][fr][kst * 32 + fg * 8];
        #pragma unroll
        for (int dt = 0; dt < 8; ++dt) {
          s16x8 vf = *(const s16x8*)&Vt[dt * 16 + fr][kst * 32 + fg * 8];
          oacc[dt] = __builtin_amdgcn_mfma_f32_16x16x32_bf16(pf, vf, oacc[dt], 0, 0, 0);
        }
      }
    }
    __syncthreads();
    if (kt < t1) {
      writelds();
    }
    __syncthreads();
  }
  #pragma unroll
  for (int j = 0; j < 4; ++j) {
    float inv = 1.f / lrun[j];
    long rofs = (tokb + wrow + fg * 4 + j) * 2048 + h * 128;
    #pragma unroll
    for (int dt = 0; dt < 8; ++dt)
      og[rofs + dt * 16 + fr] = f2b(oacc[dt][j] * inv);
  }
}

// ---------------- rmsnorm of attn_out -> x (bf16) + lr = softplus(x@lrw^T) ---
__global__ __launch_bounds__(256) void rms_lr_kernel(const float* __restrict__ src, const float* __restrict__ wgt,
                                                     const float* __restrict__ lrw, const float* __restrict__ lrbias,
                                                     u16* __restrict__ dst, float* __restrict__ lrout, float base) {
  __shared__ float red[4];
  __shared__ float red12[4][12];
  int t = blockIdx.x, tid = threadIdx.x, w = tid >> 6, l = tid & 63;
  const float* row = src + (long)t * 2048;
  float v[8] __attribute__((aligned(16)));
  ((float4*)v)[0] = *(const float4*)&row[tid * 8];
  ((float4*)v)[1] = *(const float4*)&row[tid * 8 + 4];
  float ss = 0.f;
  #pragma unroll
  for (int i = 0; i < 8; ++i) ss += v[i] * v[i];
  #pragma unroll
  for (int mk = 32; mk; mk >>= 1) ss += __shfl_xor(ss, mk, 64);
  if (l == 0) red[w] = ss;
  __syncthreads();
  float r = rsqrtf((red[0] + red[1] + red[2] + red[3]) * (1.f / 2048.f) + 1e-6f);
  float x[8];
  #pragma unroll
  for (int i = 0; i < 8; ++i) {
    x[i] = v[i] * r * wgt[tid * 8 + i];
    dst[(long)t * 2048 + tid * 8 + i] = f2b(x[i]);
  }
  float acc[12];
  #pragma unroll
  for (int j = 0; j < 12; ++j) {
    const float4* w4 = (const float4*)(lrw + j * 2048 + tid * 8);
    float4 a = w4[0], bq = w4[1];
    acc[j] = x[0] * a.x + x[1] * a.y + x[2] * a.z + x[3] * a.w +
             x[4] * bq.x + x[5] * bq.y + x[6] * bq.z + x[7] * bq.w;
  }
  #pragma unroll
  for (int j = 0; j < 12; ++j)
    #pragma unroll
    for (int mk = 32; mk; mk >>= 1) acc[j] += __shfl_xor(acc[j], mk, 64);
  if (l == 0) {
    #pragma unroll
    for (int j = 0; j < 12; ++j) red12[w][j] = acc[j];
  }
  __syncthreads();
  if (tid < 12) {
    float s_ = red12[0][tid] + red12[1][tid] + red12[2][tid] + red12[3][tid] + lrbias[tid] + base;
    lrout[(long)t * 12 + tid] = (s_ > 20.f) ? s_ : log1pf(__expf(s_));
  }
}

// ---------------- silu + l2-normalize fq/fk, silu fv -------------------------
__global__ __launch_bounds__(256) void silu_norm_kernel(const u16* __restrict__ fqkv,
    u16* __restrict__ fqo, u16* __restrict__ fko, u16* __restrict__ fvo) {
  int t = blockIdx.x, tid = threadIdx.x, w = tid >> 6, l = tid & 63;
  const u16* row = fqkv + (long)t * 6144;
  {
    s16x8 rv = *(const s16x8*)&row[w * 512 + l * 8];
    float x[8]; float ss = 0.f;
    #pragma unroll
    for (int i = 0; i < 8; ++i) { x[i] = siluf(b2f((u16)rv[i])); ss += x[i] * x[i]; }
    #pragma unroll
    for (int mk = 32; mk; mk >>= 1) ss += __shfl_xor(ss, mk, 64);
    float sc = 1.f / fmaxf(sqrtf(ss), 1e-6f);
    #pragma unroll
    for (int i = 0; i < 8; ++i) fqo[(long)t * 2048 + w * 512 + l * 8 + i] = f2b(x[i] * sc);
  }
  {
    s16x8 rv = *(const s16x8*)&row[2048 + w * 512 + l * 8];
    float x[8]; float ss = 0.f;
    #pragma unroll
    for (int i = 0; i < 8; ++i) { x[i] = siluf(b2f((u16)rv[i])); ss += x[i] * x[i]; }
    #pragma unroll
    for (int mk = 32; mk; mk >>= 1) ss += __shfl_xor(ss, mk, 64);
    float sc = 1.f / fmaxf(sqrtf(ss), 1e-6f);
    #pragma unroll
    for (int i = 0; i < 8; ++i) fko[(long)t * 2048 + w * 512 + l * 8 + i] = f2b(x[i] * sc);
  }
  {
    s16x8 rv = *(const s16x8*)&row[4096 + tid * 8];
    #pragma unroll
    for (int i = 0; i < 8; ++i) fvo[(long)t * 2048 + tid * 8 + i] = f2b(siluf(b2f((u16)rv[i])));
  }
}

// ---------------- init fast weights (f32 + bf16 + w1^T bf16) -----------------
__global__ __launch_bounds__(256) void winit_kernel(const float* __restrict__ w0, const float* __restrict__ w1,
                                                    const float* __restrict__ w2,
                                                    float* __restrict__ wbuf0, u16* __restrict__ wb16) {
  long gid = (long)blockIdx.x * 256 + threadIdx.x;
  long e4 = gid * 4;
  int which = (int)(e4 >> 21);
  long rem = e4 & 2097151L;
  int bh = (int)(rem >> 18);
  long idx = rem & 262143L;
  int h = bh & 3;
  const float* src = (which == 0 ? w0 : which == 1 ? w1 : w2) + (long)h * 262144 + idx;
  float4 v = *(const float4*)src;
  *(float4*)(wbuf0 + e4) = v;
  u16 o[4] __attribute__((aligned(8))) = {f2b(v.x), f2b(v.y), f2b(v.z), f2b(v.w)};
  *(s16x4*)&wb16[e4] = *(const s16x4*)o;
  if (which == 1) {
    u16* wt = wb16 + 3L * 2097152 + (long)bh * 262144;
    int r = (int)(idx >> 9), c = (int)(idx & 511);
    wt[(long)(c + 0) * 512 + r] = o[0];
    wt[(long)(c + 1) * 512 + r] = o[1];
    wt[(long)(c + 2) * 512 + r] = o[2];
    wt[(long)(c + 3) * 512 + r] = o[3];
  }
}

// ---------------- TTT per-chunk elementwise + transposed bf16 outputs --------
__global__ __launch_bounds__(256) void ttt_elem_kernel(
    const float* __restrict__ t5, u16* __restrict__ hqb,
    u16* __restrict__ hidT, u16* __restrict__ dhbmT, u16* __restrict__ dgpT,
    const u16* __restrict__ fk, const u16* __restrict__ fv, const float* __restrict__ lr,
    u16* __restrict__ k0T, u16* __restrict__ k2T, u16* __restrict__ v1T, int ic) {
  __shared__ u16 T0[64][72], T1[64][72], T2[64][72];
  int tid = threadIdx.x;
  int bh = blockIdx.y, b = bh >> 2, h = bh & 3;
  int tc = (blockIdx.x >> 3) * 64, te = (blockIdx.x & 7) * 64;
  int r = tid >> 2, c0 = (tid & 3) * 16;
  long base = (long)bh * 262144 + (long)(tc + r) * 512 + te + c0;

  {
    float gq_[16] __attribute__((aligned(16)));
    float q2_[16] __attribute__((aligned(16)));
    const float* pgq = t5 + base;
    const float* pq2 = t5 + 2097152L + base;
    #pragma unroll
    for (int q4 = 0; q4 < 4; ++q4) {
      ((float4*)gq_)[q4] = *(const float4*)(pgq + q4 * 4);
      ((float4*)q2_)[q4] = *(const float4*)(pq2 + q4 * 4);
    }
    u16 hq_[16] __attribute__((aligned(16)));
    #pragma unroll
    for (int i = 0; i < 16; ++i) hq_[i] = f2b(siluf(gq_[i]) * q2_[i]);
    *(s16x8*)&hqb[base] = ((const s16x8*)hq_)[0];
    *(s16x8*)&hqb[base + 8] = ((const s16x8*)hq_)[1];
  }
  {
    float gk_[16] __attribute__((aligned(16)));
    float k2_[16] __attribute__((aligned(16)));
    float dh_[16] __attribute__((aligned(16)));
    const float* pgk = t5 + 2L * 2097152 + base;
    const float* pk2 = t5 + 3L * 2097152 + base;
    const float* pdh = t5 + 4L * 2097152 + base;
    #pragma unroll
    for (int q4 = 0; q4 < 4; ++q4) {
      ((float4*)gk_)[q4] = *(const float4*)(pgk + q4 * 4);
      ((float4*)k2_)[q4] = *(const float4*)(pk2 + q4 * 4);
      ((float4*)dh_)[q4] = *(const float4*)(pdh + q4 * 4);
    }
    #pragma unroll
    for (int i = 0; i < 16; ++i) {
      float sg = 1.f / (1.f + __expf(-gk_[i]));
      float sil = gk_[i] * sg;
      float hid = sil * k2_[i];
      float dhbm = dh_[i] * sil;
      float dgate = dh_[i] * k2_[i];
      float dgp = dgate * sg * (1.f + gk_[i] * (1.f - sg));
      T0[r][c0 + i] = f2b(hid);
      T1[r][c0 + i] = f2b(dhbm);
      T2[r][c0 + i] = f2b(dgp);
    }
  }
  __syncthreads();
  long obase = (long)bh * 262144 + (long)(te + r) * 512 + tc + c0;
  {
    u16 a0[16] __attribute__((aligned(16))), a1[16] __attribute__((aligned(16))), a2[16] __attribute__((aligned(16)));
    #pragma unroll
    for (int i = 0; i < 16; ++i) { a0[i] = T0[c0 + i][r]; a1[i] = T1[c0 + i][r]; a2[i] = T2[c0 + i][r]; }
    *(s16x8*)&hidT[obase] = ((const s16x8*)a0)[0];   *(s16x8*)&hidT[obase + 8] = ((const s16x8*)a0)[1];
    *(s16x8*)&dhbmT[obase] = ((const s16x8*)a1)[0];  *(s16x8*)&dhbmT[obase + 8] = ((const s16x8*)a1)[1];
    *(s16x8*)&dgpT[obase] = ((const s16x8*)a2)[0];   *(s16x8*)&dgpT[obase + 8] = ((const s16x8*)a2)[1];
  }
  __syncthreads();
  {
    long to = (long)b * 2048 + (long)ic * 512 + tc + r;
    float l0 = lr[to * 12 + h], l1 = lr[to * 12 + 4 + h], l2 = lr[to * 12 + 8 + h];
    long goff = to * 2048 + (long)h * 512 + te + c0;
    s16x8 ka = *(const s16x8*)&fk[goff];
    s16x8 kb8 = *(const s16x8*)&fk[goff + 8];
    s16x8 va = *(const s16x8*)&fv[goff];
    s16x8 vb8 = *(const s16x8*)&fv[goff + 8];
    #pragma unroll
    for (int i = 0; i < 8; ++i) {
      float kv1 = b2f((u16)ka[i]), kv2 = b2f((u16)kb8[i]);
      float vv1 = b2f((u16)va[i]), vv2 = b2f((u16)vb8[i]);
      T0[r][c0 + i] = f2b(kv1 * l0);      T0[r][c0 + 8 + i] = f2b(kv2 * l0);
      T1[r][c0 + i] = f2b(kv1 * l2);      T1[r][c0 + 8 + i] = f2b(kv2 * l2);
      T2[r][c0 + i] = f2b(vv1 * l1);      T2[r][c0 + 8 + i] = f2b(vv2 * l1);
    }
  }
  __syncthreads();
  {
    u16 a0[16] __attribute__((aligned(16))), a1[16] __attribute__((aligned(16))), a2[16] __attribute__((aligned(16)));
    #pragma unroll
    for (int i = 0; i < 16; ++i) { a0[i] = T0[c0 + i][r]; a1[i] = T1[c0 + i][r]; a2[i] = T2[c0 + i][r]; }
    *(s16x8*)&k0T[obase] = ((const s16x8*)a0)[0];  *(s16x8*)&k0T[obase + 8] = ((const s16x8*)a0)[1];
    *(s16x8*)&k2T[obase] = ((const s16x8*)a1)[0];  *(s16x8*)&k2T[obase + 8] = ((const s16x8*)a1)[1];
    *(s16x8*)&v1T[obase] = ((const s16x8*)a2)[0];  *(s16x8*)&v1T[obase + 8] = ((const s16x8*)a2)[1];
  }
}

// ---------------- o_fw rmsnorm (per token per head over 512) -----------------
__global__ __launch_bounds__(256) void ttt_norm_kernel(const u16* __restrict__ src, const float* __restrict__ wgt,
                                                       u16* __restrict__ dst) {
  int t = blockIdx.x, tid = threadIdx.x, w = tid >> 6, l = tid & 63;
  long off = (long)t * 2048 + w * 512 + l * 8;
  s16x8 rv = *(const s16x8*)&src[off];
  float x[8];
  float ss = 0.f;
  #pragma unroll
  for (int i = 0; i < 8; ++i) { x[i] = b2f((u16)rv[i]); ss += x[i] * x[i]; }
  #pragma unroll
  for (int mk = 32; mk; mk >>= 1) ss += __shfl_xor(ss, mk, 64);
  float r = rsqrtf(ss * (1.f / 512.f) + 1e-6f);
  #pragma unroll
  for (int i = 0; i < 8; ++i) dst[off + i] = f2b(x[i] * r * wgt[l * 8 + i]);
}

// =============================================================================
extern "C" void kernel_launch(void* const* d_in, const int* in_sizes, int n_in,
                              void* d_out, int out_size, void* d_ws, size_t ws_size,
                              hipStream_t stream) {
  const float* hidden     = (const float*)d_in[0];
  const float* attn_qkv_w = (const float*)d_in[1];
  const float* attn_o_w   = (const float*)d_in[2];
  const float* q_norm_w   = (const float*)d_in[3];
  const float* k_norm_w   = (const float*)d_in[4];
  const float* mlp_norm_w = (const float*)d_in[5];
  const float* mlp_qkv_w  = (const float*)d_in[6];
  const float* mlp_o_w    = (const float*)d_in[7];
  const float* lr_w       = (const float*)d_in[8];
  const float* lr_bias    = (const float*)d_in[9];
  const float* w0in       = (const float*)d_in[10];
  const float* w1in       = (const float*)d_in[11];
  const float* w2in       = (const float*)d_in[12];
  const float* ttt_w      = (const float*)d_in[13];
  float* out = (float*)d_out;

  char* ws = (char*)d_ws;
  u16* hbf   = (u16*)(ws + 0);             // 16.78 MB: hidden bf16 -> xb -> ofw
  u16* wqb   = (u16*)(ws + 16777216);      // 25.17 MB: attn_qkv_w -> mlp_qkv_w bf16
  u16* wob   = (u16*)(ws + 41943040);      //  8.39 MB: attn_o_w -> mlp_o_w bf16
  char* big  = ws + 50331648;              // 71.30 MB: qkv/fqkv bf16 + vT -> TTT temps
  u16* qbuf  = (u16*)(ws + 121634816);     // q -> fq
  u16* kbuf  = (u16*)(ws + 138412032);     // k -> fk
  u16* vbuf  = (u16*)(ws + 155189248);     // v -> fv
  u16* obuf  = (u16*)(ws + 171966464);     // attn o bf16 -> o_fw_norm bf16
  float* lrb_ = (float*)(ws + 188743680);  // 196608 B
  float* wbuf = (float*)(ws + 188940288);  // 50.33 MB: fast weights f32 ping-pong
  u16* wb16  = (u16*)(ws + 239271936);     // 16.78 MB: w0b,w1b,w2b,w1Tb
  // total: 256,049,152 bytes (~244.2 MiB)

  u16* qkvb = (u16*)big;
  u16* vTb  = (u16*)(big + 50331648);      // 16.78 MB V^T (only live during attn)
  float* t5 = (float*)big;
  u16* hqb   = (u16*)(big + 41943040);
  u16* hidT  = (u16*)(big + 46137344);
  u16* dhbmT = (u16*)(big + 50331648);
  u16* dgpT  = (u16*)(big + 54525952);
  u16* k0T   = (u16*)(big + 58720256);
  u16* k2T   = (u16*)(big + 62914560);
  u16* v1T   = (u16*)(big + 67108864);
  u16* xb  = hbf;
  u16* ofw = hbf;

  // 1: convert hidden + attn weights to bf16 (one 3-range launch)
  convk3<<<24576, 256, 0, stream>>>(hidden, hbf, 8388608L,
                                    attn_qkv_w, wqb, 12582912L,
                                    attn_o_w, wob);
  // 4: qkv = hidden @ attn_qkv_w^T (bf16 out) — 256^2 ring-4 deep GEMM
  gemm_deep<0><<<384, 512, 0, stream>>>(hbf, wqb, qkvb, nullptr, 6144, 2048, 24);
  // 5: q/k rmsnorm + rope, v passthrough
  norm_rope_kernel<<<4096, 256, 0, stream>>>(qkvb, q_norm_w, k_norm_w, qbuf, kbuf, vbuf);
  // 5b: transpose V -> vT [b,h,d,t]
  vtrans_kernel<<<dim3(32, 2, 32), 256, 0, stream>>>(vbuf, vTb);
  // 6: sliding-window attention (64-row q blocks, bh-grouped XCD mapping)
  attn_kernel<<<dim3(32, 16, 2), 256, 0, stream>>>(qbuf, kbuf, vTb, obuf);
  // 7: attn_out = o @ attn_o_w^T -> d_out (f32)
  gemm128<1><<<512, 256, 0, stream>>>(obuf, wob, out, nullptr, 2048, 2048, 16);
  // 8: x = rmsnorm(attn_out) + lr = softplus(x@lr_w^T+...) fused
  float base_lr_inv = 0.001f + logf(-expm1f(-0.001f));
  rms_lr_kernel<<<4096, 256, 0, stream>>>(out, mlp_norm_w, lr_w, lr_bias, xb, lrb_, base_lr_inv);
  // 9: convert mlp weights (one 3-range launch; third range aliases tail)
  convk3<<<16384, 256, 0, stream>>>(mlp_qkv_w, wqb, 12582912L,
                                    mlp_o_w, wob, 4194304L,
                                    mlp_o_w, wob);
  // 11: fqkv = x @ mlp_qkv_w^T (bf16 out)
  gemm_deep<0><<<384, 512, 0, stream>>>(xb, wqb, qkvb, nullptr, 6144, 2048, 24);
  // 12: silu + normalize -> fq/fk/fv
  silu_norm_kernel<<<4096, 256, 0, stream>>>(qkvb, qbuf, kbuf, vbuf);
  // 13: init fast weights
  winit_kernel<<<6144, 256, 0, stream>>>(w0in, w1in, w2in, wbuf, wb16);

  // 14: TTT scan over 4 chunks
  for (int ic = 0; ic < 4; ++ic) {
    // G1: gq,q2,gk,k2,dhid  (5 gemms x 8 bh)
    {
      GemmBatch g{}; g.nbh = 8;
      const u16* Asrc[5] = {qbuf, qbuf, kbuf, kbuf, vbuf};
      long Bwhich[5] = {0, 2, 0, 2, 3};
      for (int i = 0; i < 5; ++i) {
        GemmDesc& dd = g.d[i];
        dd.A = Asrc[i] + (long)ic * 1048576; dd.sAb = 4194304; dd.sAh = 512; dd.lda = 2048;
        dd.B = wb16 + Bwhich[i] * 2097152;   dd.sBb = 1048576; dd.sBh = 262144; dd.ldb = 512;
        dd.C = t5 + (long)i * 2097152;       dd.sCb_ = 1048576; dd.sCh_ = 262144; dd.ldc = 512;
        dd.K = 512;
      }
      gemm_bt<<<dim3(4, 4, 40), 256, 0, stream>>>(g);
    }
    // E: elementwise + transposed bf16 outputs
    ttt_elem_kernel<<<dim3(64, 8), 256, 0, stream>>>(t5, hqb, hidT, dhbmT, dgpT,
                                                     kbuf, vbuf, lrb_, k0T, k2T, v1T, ic);
    // G2+G3 merged: oc GEMM + 3 weight-update GEMMs in one launch
    {
      GemmBatch g{}; g.nbh = 8;
      float* wc_ = wbuf + (long)(ic & 1) * 6291456;
      float* wn_ = wbuf + (long)((ic & 1) ^ 1) * 6291456;
      {
        GemmDesc& dd = g.d[0];
        dd.A = hqb; dd.sAb = 1048576; dd.sAh = 262144; dd.lda = 512;
        dd.B = wb16 + 2097152; dd.sBb = 1048576; dd.sBh = 262144; dd.ldb = 512;
        dd.Cb = ofw + (long)ic * 1048576; dd.sCbb = 4194304; dd.sCbh = 512; dd.ldcb = 2048;
        dd.K = 512;
      }
      const u16* A3[3] = {dgpT, v1T, dhbmT};
      const u16* B3[3] = {k0T, hidT, k2T};
      for (int i = 0; i < 3; ++i) {
        GemmDesc& dd = g.d[1 + i];
        dd.A = A3[i]; dd.sAb = 1048576; dd.sAh = 262144; dd.lda = 512;
        dd.B = B3[i]; dd.sBb = 1048576; dd.sBh = 262144; dd.ldb = 512;
        dd.Cin = wc_ + (long)i * 2097152; dd.C = wn_ + (long)i * 2097152;
        dd.sCb_ = 1048576; dd.sCh_ = 262144; dd.ldc = 512;
        dd.Cb = wb16 + (long)i * 2097152; dd.sCbb = 1048576; dd.sCbh = 262144; dd.ldcb = 512;
        if (i == 1) { dd.CbT = wb16 + 3L * 2097152; dd.sCtb = 1048576; dd.sCth = 262144; dd.ldct = 512; }
        dd.K = 512;
      }
      gemm_bt<<<dim3(4, 4, 32), 256, 0, stream>>>(g);
    }
  }
  // 15: o_fw rmsnorm
  ttt_norm_kernel<<<4096, 256, 0, stream>>>(ofw, ttt_w, obuf);
  // 16: d_out += o_fw_norm @ mlp_o_w^T
  gemm128<2><<<512, 256, 0, stream>>>(obuf, wob, out, out, 2048, 2048, 16);
  (void)in_sizes; (void)n_in; (void)out_size; (void)ws_size;
}